// Round 1
// baseline (712.011 us; speedup 1.0000x reference)
//
#include <hip/hip_runtime.h>
#include <hip/hip_bf16.h>
#include <math.h>

#define BATCH 2
#define CCH 64
#define HH 64
#define WW 64
#define RR 32
#define HWD 4096
#define NSIDE 2

// ws layout (floats):
//   theta: [side][b][q][32]   524288
//   phi:   [side][b][k][32]   524288
//   g:     [side][b][k][32]   524288
//   a:     [side][b][q][32]   524288
// total 2097152 floats = 8 MB

__global__ __launch_bounds__(256) void prep_kernel(
    const float* __restrict__ left, const float* __restrict__ right,
    const float* __restrict__ pre_l, const float* __restrict__ pre_r,
    const float* __restrict__ query_l, const float* __restrict__ key_l,
    const float* __restrict__ query_r, const float* __restrict__ key_r,
    const float* __restrict__ w_theta, const float* __restrict__ b_theta,
    const float* __restrict__ w_phi, const float* __restrict__ b_phi,
    const float* __restrict__ w_g, const float* __restrict__ b_g,
    float* __restrict__ theta, float* __restrict__ phi, float* __restrict__ g)
{
    __shared__ float wt_s[65][RR];
    __shared__ float wp_s[64][RR];
    __shared__ float wg_s[64][RR];
    int tid = threadIdx.x;
    for (int i = tid; i < 65 * RR; i += 256) {
        int r = i / 65, c = i % 65;
        wt_s[c][r] = w_theta[i];
    }
    for (int i = tid; i < 64 * RR; i += 256) {
        int r = i >> 6, c = i & 63;
        wp_s[c][r] = w_phi[i];
        wg_s[c][r] = w_g[i];
    }
    __syncthreads();

    int t = blockIdx.x * 256 + tid;          // 0..16383
    int side = t >> 13;
    int b = (t >> 12) & 1;
    int p = t & 4095;

    const float* xq   = side ? right   : left;
    const float* xk   = side ? left    : right;
    const float* pre  = side ? pre_r   : pre_l;
    const float* qadd = side ? query_r : query_l;
    const float* kadd = side ? key_l   : key_r;

    float ta[RR], pa[RR], ga[RR];
    #pragma unroll
    for (int r = 0; r < RR; ++r) { ta[r] = 0.f; pa[r] = 0.f; ga[r] = 0.f; }

    for (int c = 0; c < CCH; ++c) {
        float xqv = xq[((size_t)b * CCH + c) * HWD + p];
        float xkv = xk[((size_t)b * CCH + c) * HWD + p];
        #pragma unroll
        for (int r = 0; r < RR; ++r) {
            ta[r] += wt_s[c][r] * xqv;
            pa[r] += wp_s[c][r] * xkv;
            ga[r] += wg_s[c][r] * xkv;
        }
    }

    float pv = pre[(size_t)b * HWD + p] * (1.0f / (float)WW);
    size_t base = ((size_t)(side * BATCH + b) * HWD + p) * RR;
    #pragma unroll
    for (int r = 0; r < RR; ++r) {
        theta[base + r] = ta[r] + wt_s[64][r] * pv + b_theta[r]
                          + qadd[((size_t)b * RR + r) * HWD + p];
        phi[base + r] = pa[r] + b_phi[r] + kadd[((size_t)b * RR + r) * HWD + p];
        g[base + r] = ga[r] + b_g[r];
    }
}

#define QT 16
#define KT 64

__global__ __launch_bounds__(256) void attn_kernel(
    const float* __restrict__ theta, const float* __restrict__ phi,
    const float* __restrict__ g, float* __restrict__ a,
    float* __restrict__ d_out)
{
    __shared__ float phi_s[KT][RR + 1];
    __shared__ float g_s[KT][RR + 1];

    int tid = threadIdx.x;
    int bid = blockIdx.x;                 // 0..1023
    int side = bid >> 9;
    int b = (bid >> 8) & 1;
    int q0 = (bid & 255) * QT;
    int sb = side * BATCH + b;

    const float* th_base = theta + (size_t)sb * HWD * RR;
    const float* ph_base = phi + (size_t)sb * HWD * RR;
    const float* g_base  = g + (size_t)sb * HWD * RR;

    int ql = tid >> 4;   // 0..15 : query within tile
    int kl = tid & 15;   // 0..15 : key lane within query group
    int q = q0 + ql;

    float tr[RR];
    #pragma unroll
    for (int r = 0; r < RR; ++r) tr[r] = th_base[(size_t)q * RR + r];

    float m = -1e30f, s = 0.f, ec = 0.f;
    float acc[RR];
    #pragma unroll
    for (int r = 0; r < RR; ++r) acc[r] = 0.f;

    for (int kc = 0; kc < HWD / KT; ++kc) {
        __syncthreads();
        for (int i = tid; i < KT * RR; i += 256) {
            int k = i >> 5, r = i & 31;
            phi_s[k][r] = ph_base[(size_t)kc * KT * RR + i];
            g_s[k][r]   = g_base[(size_t)kc * KT * RR + i];
        }
        __syncthreads();

        float l[4];
        #pragma unroll
        for (int j = 0; j < 4; ++j) {
            int k = kl * 4 + j;
            float d = 0.f;
            #pragma unroll
            for (int r = 0; r < RR; ++r) d += tr[r] * phi_s[k][r];
            l[j] = d;
        }
        float lm = fmaxf(fmaxf(l[0], l[1]), fmaxf(l[2], l[3]));
        #pragma unroll
        for (int off = 8; off >= 1; off >>= 1)
            lm = fmaxf(lm, __shfl_xor(lm, off, 16));
        float nm = fmaxf(m, lm);
        float sc = __expf(m - nm);
        m = nm;
        s *= sc; ec *= sc;
        #pragma unroll
        for (int r = 0; r < RR; ++r) acc[r] *= sc;

        #pragma unroll
        for (int j = 0; j < 4; ++j) {
            int k = kl * 4 + j;
            float p = __expf(l[j] - m);
            s += p;
            int kg = kc * KT + k;
            ec += p * (float)(kg & 63);
            #pragma unroll
            for (int r = 0; r < RR; ++r) acc[r] += p * g_s[k][r];
        }
    }

    // reduce within 16-lane query groups
    #pragma unroll
    for (int off = 8; off >= 1; off >>= 1) {
        s  += __shfl_xor(s, off, 16);
        ec += __shfl_xor(ec, off, 16);
    }
    #pragma unroll
    for (int r = 0; r < RR; ++r) {
        #pragma unroll
        for (int off = 8; off >= 1; off >>= 1)
            acc[r] += __shfl_xor(acc[r], off, 16);
    }

    float inv_s = 1.0f / s;
    if (kl == 0) {
        float* ap = a + ((size_t)sb * HWD + q) * RR;
        #pragma unroll
        for (int r = 0; r < RR; ++r) ap[r] = acc[r] * inv_s;
        // index output: (q % W) - exp_col
        float idx = (float)(q & 63) - ec * inv_s;
        float* idx_out = d_out + (size_t)2 * BATCH * CCH * HWD
                         + (size_t)side * BATCH * HWD + (size_t)b * HWD + q;
        *idx_out = idx;
    }
}

__global__ __launch_bounds__(256) void bn_kernel(
    const float* __restrict__ left, const float* __restrict__ right,
    const float* __restrict__ a, const float* __restrict__ w_up,
    const float* __restrict__ b_up, const float* __restrict__ gamma,
    const float* __restrict__ beta, float* __restrict__ d_out)
{
    __shared__ double red[256];
    __shared__ double red2[256];
    int side = blockIdx.x >> 6;
    int o = blockIdx.x & 63;
    int tid = threadIdx.x;

    float wu[RR];
    #pragma unroll
    for (int r = 0; r < RR; ++r) wu[r] = w_up[o * RR + r];
    float bu = b_up[o];

    const float* ab = a + (size_t)side * BATCH * HWD * RR;

    double sum = 0.0, sumsq = 0.0;
    for (int i = tid; i < BATCH * HWD; i += 256) {
        const float* ap = ab + (size_t)i * RR;
        float y = bu;
        #pragma unroll
        for (int r = 0; r < RR; ++r) y += wu[r] * ap[r];
        sum += (double)y;
        sumsq += (double)y * (double)y;
    }
    red[tid] = sum; red2[tid] = sumsq;
    __syncthreads();
    for (int st = 128; st >= 1; st >>= 1) {
        if (tid < st) { red[tid] += red[tid + st]; red2[tid] += red2[tid + st]; }
        __syncthreads();
    }
    double mean = red[0] / (double)(BATCH * HWD);
    double var = red2[0] / (double)(BATCH * HWD) - mean * mean;
    float scale = gamma[o] / sqrtf((float)var + 1e-5f);
    float mf = (float)mean;
    float bt = beta[o];

    const float* x = side ? right : left;
    float* outp = d_out + (size_t)side * (BATCH * CCH * HWD);

    for (int i = tid; i < BATCH * HWD; i += 256) {
        int b = i >> 12, qq = i & 4095;
        const float* ap = ab + (size_t)i * RR;
        float y = bu;
        #pragma unroll
        for (int r = 0; r < RR; ++r) y += wu[r] * ap[r];
        float xv = x[((size_t)b * CCH + o) * HWD + qq];
        outp[((size_t)b * CCH + o) * HWD + qq] = xv + (y - mf) * scale + bt;
    }
}

extern "C" void kernel_launch(void* const* d_in, const int* in_sizes, int n_in,
                              void* d_out, int out_size, void* d_ws, size_t ws_size,
                              hipStream_t stream)
{
    const float* left    = (const float*)d_in[0];
    const float* right   = (const float*)d_in[1];
    const float* pre_l   = (const float*)d_in[2];
    const float* pre_r   = (const float*)d_in[3];
    const float* query_l = (const float*)d_in[4];
    const float* key_l   = (const float*)d_in[5];
    const float* query_r = (const float*)d_in[6];
    const float* key_r   = (const float*)d_in[7];
    const float* w_theta = (const float*)d_in[8];
    const float* b_theta = (const float*)d_in[9];
    const float* w_phi   = (const float*)d_in[10];
    const float* b_phi   = (const float*)d_in[11];
    const float* w_g     = (const float*)d_in[12];
    const float* b_g     = (const float*)d_in[13];
    const float* w_up    = (const float*)d_in[14];
    const float* b_up    = (const float*)d_in[15];
    const float* gamma   = (const float*)d_in[16];
    const float* beta    = (const float*)d_in[17];

    float* ws = (float*)d_ws;
    float* theta = ws;
    float* phi   = ws + 524288;
    float* g     = ws + 1048576;
    float* a     = ws + 1572864;

    prep_kernel<<<64, 256, 0, stream>>>(left, right, pre_l, pre_r,
                                        query_l, key_l, query_r, key_r,
                                        w_theta, b_theta, w_phi, b_phi,
                                        w_g, b_g, theta, phi, g);
    attn_kernel<<<1024, 256, 0, stream>>>(theta, phi, g, a, (float*)d_out);
    bn_kernel<<<128, 256, 0, stream>>>(left, right, a, w_up, b_up,
                                       gamma, beta, (float*)d_out);
}

// Round 2
// 185.968 us; speedup vs baseline: 3.8287x; 3.8287x over previous
//
#include <hip/hip_runtime.h>
#include <hip/hip_bf16.h>
#include <math.h>

#define BATCH 2
#define CCH 64
#define WW 64
#define RR 32
#define HWD 4096
#define NSB 4
#define SPLITS 4
#define KEYS_PER_SPLIT (HWD / SPLITS)   // 1024
#define KB 32                           // keys per inner block

typedef __attribute__((ext_vector_type(8))) short bf16x8;
typedef __attribute__((ext_vector_type(4))) float f32x4;

__device__ __forceinline__ ushort f2b(float x) {
    __hip_bfloat16 h = __float2bfloat16(x);
    return *reinterpret_cast<ushort*>(&h);
}
__device__ __forceinline__ uint pk2(float a, float b) {
    return (uint)f2b(a) | ((uint)f2b(b) << 16);
}

// ---------------------------------------------------------------------------
// prep: three 1x1 convs -> theta/phi (bf16 [sb][4096][32]) and gT (bf16 [sb][32][4096])
// ---------------------------------------------------------------------------
__global__ __launch_bounds__(256) void prep_kernel(
    const float* __restrict__ left, const float* __restrict__ right,
    const float* __restrict__ pre_l, const float* __restrict__ pre_r,
    const float* __restrict__ query_l, const float* __restrict__ key_l,
    const float* __restrict__ query_r, const float* __restrict__ key_r,
    const float* __restrict__ w_theta, const float* __restrict__ b_theta,
    const float* __restrict__ w_phi, const float* __restrict__ b_phi,
    const float* __restrict__ w_g, const float* __restrict__ b_g,
    ushort* __restrict__ thetaB, ushort* __restrict__ phiB,
    ushort* __restrict__ gTB)
{
    __shared__ float wt_s[65][RR];
    __shared__ float wp_s[64][RR];
    __shared__ float wg_s[64][RR];
    int tid = threadIdx.x;
    for (int i = tid; i < 65 * RR; i += 256) {
        int r = i / 65, c = i % 65;
        wt_s[c][r] = w_theta[i];
    }
    for (int i = tid; i < 64 * RR; i += 256) {
        int r = i >> 6, c = i & 63;
        wp_s[c][r] = w_phi[i];
        wg_s[c][r] = w_g[i];
    }
    __syncthreads();

    int t = blockIdx.x * 256 + tid;          // 0..16383
    int side = t >> 13;
    int b = (t >> 12) & 1;
    int p = t & 4095;
    int sb = t >> 12;                        // side*2 + b

    const float* xq   = side ? right   : left;
    const float* xk   = side ? left    : right;
    const float* pre  = side ? pre_r   : pre_l;
    const float* qadd = side ? query_r : query_l;
    const float* kadd = side ? key_l   : key_r;

    float ta[RR], pa[RR], ga[RR];
    #pragma unroll
    for (int r = 0; r < RR; ++r) { ta[r] = 0.f; pa[r] = 0.f; ga[r] = 0.f; }

    for (int c = 0; c < CCH; ++c) {
        float xqv = xq[((size_t)b * CCH + c) * HWD + p];
        float xkv = xk[((size_t)b * CCH + c) * HWD + p];
        #pragma unroll
        for (int r = 0; r < RR; ++r) {
            ta[r] += wt_s[c][r] * xqv;
            pa[r] += wp_s[c][r] * xkv;
            ga[r] += wg_s[c][r] * xkv;
        }
    }

    float pv = pre[(size_t)b * HWD + p] * (1.0f / (float)WW);
    size_t rowbase = ((size_t)sb * HWD + p) * RR;
    #pragma unroll
    for (int r = 0; r < RR; ++r) {
        thetaB[rowbase + r] = f2b(ta[r] + wt_s[64][r] * pv + b_theta[r]
                                  + qadd[((size_t)b * RR + r) * HWD + p]);
        phiB[rowbase + r] = f2b(pa[r] + b_phi[r]
                                + kadd[((size_t)b * RR + r) * HWD + p]);
        gTB[((size_t)sb * RR + r) * HWD + p] = f2b(ga[r] + b_g[r]);
    }
}

// ---------------------------------------------------------------------------
// attn: MFMA QK^T -> exp -> MFMA PV, kv-split=4, unnormalized accumulation
// grid: 1024 blocks x 256 thr (4 waves). block -> (sb, split, 4 q-tiles)
// ---------------------------------------------------------------------------
__global__ __launch_bounds__(256, 4) void attn_kernel(
    const ushort* __restrict__ thetaB, const ushort* __restrict__ phiB,
    const ushort* __restrict__ gTB,
    float* __restrict__ accA, float* __restrict__ sS, float* __restrict__ ecE)
{
    // per-wave P tile: [16 q][36 bf16] (32 keys + pad; stride 36 -> <=2-way banks)
    __shared__ ushort P_lds[4][16][36];

    int tid = threadIdx.x;
    int w = tid >> 6;
    int l = tid & 63;
    int ql = l & 15;
    int kgrp = l >> 4;

    int blk = blockIdx.x;          // 0..1023
    int sb = blk >> 8;             // 0..3
    int rem = blk & 255;
    int split = rem & 3;           // waves in block share the key range
    int qg = rem >> 2;             // 0..63
    int qt = qg * 4 + w;           // q-tile 0..255
    int q = qt * 16 + ql;

    // B-frag: theta^T  (col = q = lane&15, k(=r) = kgrp*8..+8)
    bf16x8 bfrag = *(const bf16x8*)(thetaB + ((size_t)sb * HWD + q) * RR + kgrp * 8);

    const ushort* phb = phiB + (size_t)sb * HWD * RR;
    const ushort* gtb = gTB + (size_t)sb * RR * HWD;

    f32x4 acc0 = {0.f, 0.f, 0.f, 0.f};
    f32x4 acc1 = {0.f, 0.f, 0.f, 0.f};
    const f32x4 zero = {0.f, 0.f, 0.f, 0.f};
    float ssum = 0.f, esum = 0.f;

    int k0 = split * KEYS_PER_SPLIT;
    for (int kb = 0; kb < KEYS_PER_SPLIT / KB; ++kb) {
        int kbase = k0 + kb * KB;

        // A-frags: phi rows (row = key = lane&15, k(=r) = kgrp*8..+8)
        bf16x8 a0 = *(const bf16x8*)(phb + ((size_t)(kbase + ql) * RR) + kgrp * 8);
        bf16x8 a1 = *(const bf16x8*)(phb + ((size_t)(kbase + 16 + ql) * RR) + kgrp * 8);

        // S[key][q]: lane holds q = lane&15, keys = 16d + kgrp*4 + reg
        f32x4 s0 = __builtin_amdgcn_mfma_f32_16x16x32_bf16(a0, bfrag, zero, 0, 0, 0);
        f32x4 s1 = __builtin_amdgcn_mfma_f32_16x16x32_bf16(a1, bfrag, zero, 0, 0, 0);

        float p0[4], p1[4];
        float cb = (float)((kbase & 32) + kgrp * 4);
        #pragma unroll
        for (int r = 0; r < 4; ++r) {
            p0[r] = __expf(s0[r]);
            p1[r] = __expf(s1[r]);
            ssum += p0[r] + p1[r];
            esum += p0[r] * (cb + (float)r) + p1[r] * (cb + 16.0f + (float)r);
        }

        // write P (bf16) to per-wave LDS tile: [q][key_local]
        ushort* prow = &P_lds[w][ql][0];
        #pragma unroll
        for (int t = 0; t < 2; ++t) {
            *(uint*)(prow + kgrp * 4 + 2 * t)      = pk2(p0[2 * t], p0[2 * t + 1]);
            *(uint*)(prow + 16 + kgrp * 4 + 2 * t) = pk2(p1[2 * t], p1[2 * t + 1]);
        }

        // B2-frag: P[k_local][q] (col = q = lane&15, k = kgrp*8 + j)
        union { bf16x8 v; uint u[4]; } b2;
        const uint* psrc = (const uint*)(&P_lds[w][ql][0]);
        #pragma unroll
        for (int t = 0; t < 4; ++t) b2.u[t] = psrc[kgrp * 4 + t];

        // A2-frags: gT rows (row = r' = lane&15 (+16), k = keys kgrp*8..+8)
        bf16x8 a2_0 = *(const bf16x8*)(gtb + (size_t)ql * HWD + kbase + kgrp * 8);
        bf16x8 a2_1 = *(const bf16x8*)(gtb + (size_t)(16 + ql) * HWD + kbase + kgrp * 8);

        acc0 = __builtin_amdgcn_mfma_f32_16x16x32_bf16(a2_0, b2.v, acc0, 0, 0, 0);
        acc1 = __builtin_amdgcn_mfma_f32_16x16x32_bf16(a2_1, b2.v, acc1, 0, 0, 0);
    }

    // reduce s / ec over the 4 key-lane groups (same q)
    ssum += __shfl_xor(ssum, 16);
    ssum += __shfl_xor(ssum, 32);
    esum += __shfl_xor(esum, 16);
    esum += __shfl_xor(esum, 32);

    // accumulate across splits: out[r][q] -> accA[sb][q][r]
    float* accp = accA + ((size_t)sb * HWD + q) * RR;
    #pragma unroll
    for (int r = 0; r < 4; ++r) {
        atomicAdd(accp + kgrp * 4 + r, acc0[r]);
        atomicAdd(accp + 16 + kgrp * 4 + r, acc1[r]);
    }
    if (l < 16) {
        atomicAdd(sS + (size_t)sb * HWD + q, ssum);
        atomicAdd(ecE + (size_t)sb * HWD + q, esum);
    }
}

// ---------------------------------------------------------------------------
// disparity index output
// ---------------------------------------------------------------------------
__global__ __launch_bounds__(256) void index_kernel(
    const float* __restrict__ sS, const float* __restrict__ ecE,
    float* __restrict__ d_out)
{
    int t = blockIdx.x * 256 + threadIdx.x;   // 0..16383 = sb*4096+q
    int q = t & 4095;
    float idx = (float)(q & 63) - ecE[t] / sS[t];
    d_out[(size_t)2 * BATCH * CCH * HWD + t] = idx;  // [side][b][q] == t order
}

// ---------------------------------------------------------------------------
// up-conv (divide by s inline) + training-mode BN + residual
// ---------------------------------------------------------------------------
__global__ __launch_bounds__(256) void bn_kernel(
    const float* __restrict__ left, const float* __restrict__ right,
    const float* __restrict__ accA, const float* __restrict__ sS,
    const float* __restrict__ w_up, const float* __restrict__ b_up,
    const float* __restrict__ gamma, const float* __restrict__ beta,
    float* __restrict__ d_out)
{
    __shared__ double red[256];
    __shared__ double red2[256];
    int side = blockIdx.x >> 6;
    int o = blockIdx.x & 63;
    int tid = threadIdx.x;

    float wu[RR];
    #pragma unroll
    for (int r = 0; r < RR; ++r) wu[r] = w_up[o * RR + r];
    float bu = b_up[o];

    const float* ab = accA + (size_t)side * BATCH * HWD * RR;
    const float* sp = sS + (size_t)side * BATCH * HWD;

    double sum = 0.0, sumsq = 0.0;
    for (int i = tid; i < BATCH * HWD; i += 256) {
        const float* ap = ab + (size_t)i * RR;
        float d = 0.f;
        #pragma unroll
        for (int r = 0; r < RR; ++r) d += wu[r] * ap[r];
        float y = bu + d / sp[i];
        sum += (double)y;
        sumsq += (double)y * (double)y;
    }
    red[tid] = sum; red2[tid] = sumsq;
    __syncthreads();
    for (int st = 128; st >= 1; st >>= 1) {
        if (tid < st) { red[tid] += red[tid + st]; red2[tid] += red2[tid + st]; }
        __syncthreads();
    }
    double mean = red[0] / (double)(BATCH * HWD);
    double var = red2[0] / (double)(BATCH * HWD) - mean * mean;
    float scale = gamma[o] / sqrtf((float)var + 1e-5f);
    float mf = (float)mean;
    float bt = beta[o];

    const float* x = side ? right : left;
    float* outp = d_out + (size_t)side * (BATCH * CCH * HWD);

    for (int i = tid; i < BATCH * HWD; i += 256) {
        int b = i >> 12, qq = i & 4095;
        const float* ap = ab + (size_t)i * RR;
        float d = 0.f;
        #pragma unroll
        for (int r = 0; r < RR; ++r) d += wu[r] * ap[r];
        float y = bu + d / sp[i];
        float xv = x[((size_t)b * CCH + o) * HWD + qq];
        outp[((size_t)b * CCH + o) * HWD + qq] = xv + (y - mf) * scale + bt;
    }
}

extern "C" void kernel_launch(void* const* d_in, const int* in_sizes, int n_in,
                              void* d_out, int out_size, void* d_ws, size_t ws_size,
                              hipStream_t stream)
{
    const float* left    = (const float*)d_in[0];
    const float* right   = (const float*)d_in[1];
    const float* pre_l   = (const float*)d_in[2];
    const float* pre_r   = (const float*)d_in[3];
    const float* query_l = (const float*)d_in[4];
    const float* key_l   = (const float*)d_in[5];
    const float* query_r = (const float*)d_in[6];
    const float* key_r   = (const float*)d_in[7];
    const float* w_theta = (const float*)d_in[8];
    const float* b_theta = (const float*)d_in[9];
    const float* w_phi   = (const float*)d_in[10];
    const float* b_phi   = (const float*)d_in[11];
    const float* w_g     = (const float*)d_in[12];
    const float* b_g     = (const float*)d_in[13];
    const float* w_up    = (const float*)d_in[14];
    const float* b_up    = (const float*)d_in[15];
    const float* gamma   = (const float*)d_in[16];
    const float* beta    = (const float*)d_in[17];

    char* ws = (char*)d_ws;
    ushort* thetaB = (ushort*)ws;                          // 1 MB
    ushort* phiB   = (ushort*)(ws + 1048576);              // 1 MB
    ushort* gTB    = (ushort*)(ws + 2097152);              // 1 MB
    float*  accA   = (float*)(ws + 3145728);               // 2 MB
    float*  sSv    = (float*)(ws + 3145728 + 2097152);     // 64 KB
    float*  ecEv   = (float*)(ws + 3145728 + 2097152 + 65536); // 64 KB

    // zero the accumulators (contiguous region)
    hipMemsetAsync(accA, 0, 2097152 + 65536 + 65536, stream);

    prep_kernel<<<64, 256, 0, stream>>>(left, right, pre_l, pre_r,
                                        query_l, key_l, query_r, key_r,
                                        w_theta, b_theta, w_phi, b_phi,
                                        w_g, b_g, thetaB, phiB, gTB);
    attn_kernel<<<1024, 256, 0, stream>>>(thetaB, phiB, gTB, accA, sSv, ecEv);
    index_kernel<<<64, 256, 0, stream>>>(sSv, ecEv, (float*)d_out);
    bn_kernel<<<128, 256, 0, stream>>>(left, right, accA, sSv, w_up, b_up,
                                       gamma, beta, (float*)d_out);
}

// Round 3
// 95.827 us; speedup vs baseline: 7.4302x; 1.9407x over previous
//
#include <hip/hip_runtime.h>
#include <hip/hip_bf16.h>
#include <math.h>

#define BATCH 2
#define CCH 64
#define WW 64
#define RR 32
#define HWD 4096

typedef __attribute__((ext_vector_type(8))) short bf16x8;
typedef __attribute__((ext_vector_type(4))) float f32x4;
typedef __attribute__((ext_vector_type(2))) unsigned int uint2v;

__device__ __forceinline__ ushort f2b(float x) {
    __hip_bfloat16 h = __float2bfloat16(x);
    return *reinterpret_cast<ushort*>(&h);
}
__device__ __forceinline__ uint pk2(float a, float b) {
    return (uint)f2b(a) | ((uint)f2b(b) << 16);
}

// ---------------------------------------------------------------------------
// prep: 1x1 convs. kind 0 -> theta [sb][4096][32] bf16 (+pre, +qadd)
//       kind 1 -> phi   [sb][4096][32] bf16 (+kadd)
//       kind 2 -> gT2   [sb][34][4096] bf16 (rows 32=ones, 33=col)
// ---------------------------------------------------------------------------
__global__ __launch_bounds__(256) void prep_kernel(
    const float* __restrict__ left, const float* __restrict__ right,
    const float* __restrict__ pre_l, const float* __restrict__ pre_r,
    const float* __restrict__ query_l, const float* __restrict__ key_l,
    const float* __restrict__ query_r, const float* __restrict__ key_r,
    const float* __restrict__ w_theta, const float* __restrict__ b_theta,
    const float* __restrict__ w_phi, const float* __restrict__ b_phi,
    const float* __restrict__ w_g, const float* __restrict__ b_g,
    ushort* __restrict__ thetaB, ushort* __restrict__ phiB,
    ushort* __restrict__ gT2)
{
    __shared__ float w_s[64][RR];
    __shared__ float wx_s[RR];
    __shared__ float bias_s[RR];
    int tid = threadIdx.x;
    int kind = blockIdx.x >> 6;

    if (kind == 0) {
        for (int i = tid; i < 65 * RR; i += 256) {
            int r = i / 65, c = i % 65;
            if (c < 64) w_s[c][r] = w_theta[i]; else wx_s[r] = w_theta[i];
        }
        if (tid < RR) bias_s[tid] = b_theta[tid];
    } else {
        const float* wsrc = (kind == 1) ? w_phi : w_g;
        const float* bsrc = (kind == 1) ? b_phi : b_g;
        for (int i = tid; i < 64 * RR; i += 256) {
            int r = i >> 6, c = i & 63;
            w_s[c][r] = wsrc[i];
        }
        if (tid < RR) bias_s[tid] = bsrc[tid];
    }
    __syncthreads();

    int t = (blockIdx.x & 63) * 256 + tid;   // 0..16383
    int sb = t >> 12;
    int side = sb >> 1;
    int b = sb & 1;
    int p = t & 4095;

    const float* X;
    if (kind == 0) X = side ? right : left;   // xq
    else           X = side ? left  : right;  // xk

    float acc[RR];
    #pragma unroll
    for (int r = 0; r < RR; ++r) acc[r] = bias_s[r];

    const float* xp = X + (size_t)b * CCH * HWD + p;
    for (int c = 0; c < CCH; ++c) {
        float xv = xp[(size_t)c * HWD];
        #pragma unroll
        for (int r = 0; r < RR; ++r) acc[r] += w_s[c][r] * xv;
    }

    if (kind == 0) {
        const float* pre  = side ? pre_r   : pre_l;
        const float* qadd = side ? query_r : query_l;
        float pv = pre[(size_t)b * HWD + p] * (1.0f / 64.0f);
        uint u[16];
        #pragma unroll
        for (int r = 0; r < RR; r += 2) {
            float v0 = acc[r]   + wx_s[r]   * pv + qadd[((size_t)b * RR + r)   * HWD + p];
            float v1 = acc[r+1] + wx_s[r+1] * pv + qadd[((size_t)b * RR + r+1) * HWD + p];
            u[r >> 1] = pk2(v0, v1);
        }
        uint* dst = (uint*)(thetaB + (size_t)t * RR);
        #pragma unroll
        for (int i = 0; i < 16; ++i) dst[i] = u[i];
    } else if (kind == 1) {
        const float* kadd = side ? key_l : key_r;
        uint u[16];
        #pragma unroll
        for (int r = 0; r < RR; r += 2) {
            float v0 = acc[r]   + kadd[((size_t)b * RR + r)   * HWD + p];
            float v1 = acc[r+1] + kadd[((size_t)b * RR + r+1) * HWD + p];
            u[r >> 1] = pk2(v0, v1);
        }
        uint* dst = (uint*)(phiB + (size_t)t * RR);
        #pragma unroll
        for (int i = 0; i < 16; ++i) dst[i] = u[i];
    } else {
        ushort* gdst = gT2 + (size_t)sb * 34 * HWD + p;
        #pragma unroll
        for (int r = 0; r < RR; ++r) gdst[(size_t)r * HWD] = f2b(acc[r]);
        gdst[(size_t)32 * HWD] = 0x3F80;               // 1.0 bf16
        gdst[(size_t)33 * HWD] = f2b((float)(p & 63)); // col
    }
}

// ---------------------------------------------------------------------------
// attn: block = (sb, q-pair of 32); 4 waves = key splits of 1024.
// MFMA QK^T -> exp -> swizzled P LDS -> MFMA PV (g rows 0..31 + {ones,col}).
// LDS block-reduce across waves; writes normalized accA + index output.
// ---------------------------------------------------------------------------
__global__ __launch_bounds__(256) void attn_kernel(
    const ushort* __restrict__ thetaB, const ushort* __restrict__ phiB,
    const ushort* __restrict__ gT2,
    float* __restrict__ accA, float* __restrict__ d_out)
{
    __shared__ ushort P_lds[4][2][16][64];   // 16 KB, XOR-swizzled bytes-in-row
    __shared__ float accbuf[4][2][34][17];   // 18.5 KB

    int tid = threadIdx.x;
    int w = tid >> 6, l = tid & 63;
    int ql = l & 15, kgrp = l >> 4;
    int sb = blockIdx.x >> 7;                // 512 blocks
    int qpair = blockIdx.x & 127;
    int q0 = qpair * 32;

    const ushort* thb = thetaB + (size_t)sb * HWD * RR;
    const ushort* phb = phiB + (size_t)sb * HWD * RR;
    const ushort* gtb = gT2 + (size_t)sb * 34 * HWD;

    bf16x8 bf0 = *(const bf16x8*)(thb + (size_t)(q0 + ql) * RR + kgrp * 8);
    bf16x8 bf1 = *(const bf16x8*)(thb + (size_t)(q0 + 16 + ql) * RR + kgrp * 8);

    const f32x4 zf = {0.f, 0.f, 0.f, 0.f};
    f32x4 acc00 = zf, acc01 = zf, acc02 = zf;
    f32x4 acc10 = zf, acc11 = zf, acc12 = zf;

    int swz = (ql & 7) << 4;
    char* p0base = (char*)&P_lds[w][0][ql][0];
    char* p1base = (char*)&P_lds[w][1][ql][0];

    for (int kb = 0; kb < 16; ++kb) {
        int kbase = w * 1024 + kb * 64;

        #pragma unroll
        for (int j = 0; j < 4; ++j) {
            bf16x8 aphi = *(const bf16x8*)(phb + (size_t)(kbase + 16 * j + ql) * RR + kgrp * 8);
            f32x4 s0 = __builtin_amdgcn_mfma_f32_16x16x32_bf16(aphi, bf0, zf, 0, 0, 0);
            f32x4 s1 = __builtin_amdgcn_mfma_f32_16x16x32_bf16(aphi, bf1, zf, 0, 0, 0);
            int co = (32 * j + 8 * kgrp) ^ swz;
            uint2v w0, w1;
            w0[0] = pk2(__expf(s0[0]), __expf(s0[1]));
            w0[1] = pk2(__expf(s0[2]), __expf(s0[3]));
            w1[0] = pk2(__expf(s1[0]), __expf(s1[1]));
            w1[1] = pk2(__expf(s1[2]), __expf(s1[3]));
            *(uint2v*)(p0base + co) = w0;
            *(uint2v*)(p1base + co) = w1;
        }

        #pragma unroll
        for (int kc = 0; kc < 2; ++kc) {
            int kk = kbase + kc * 32 + kgrp * 8;
            const ushort* gp = gtb + kk;
            bf16x8 g0 = *(const bf16x8*)(gp + (size_t)ql * HWD);
            bf16x8 g1 = *(const bf16x8*)(gp + (size_t)(16 + ql) * HWD);
            bf16x8 g2 = *(const bf16x8*)(gp + (size_t)((ql == 0) ? 32 : 33) * HWD);
            int co = (64 * kc + 16 * kgrp) ^ swz;
            bf16x8 pb0 = *(const bf16x8*)(p0base + co);
            bf16x8 pb1 = *(const bf16x8*)(p1base + co);
            acc00 = __builtin_amdgcn_mfma_f32_16x16x32_bf16(g0, pb0, acc00, 0, 0, 0);
            acc01 = __builtin_amdgcn_mfma_f32_16x16x32_bf16(g1, pb0, acc01, 0, 0, 0);
            acc02 = __builtin_amdgcn_mfma_f32_16x16x32_bf16(g2, pb0, acc02, 0, 0, 0);
            acc10 = __builtin_amdgcn_mfma_f32_16x16x32_bf16(g0, pb1, acc10, 0, 0, 0);
            acc11 = __builtin_amdgcn_mfma_f32_16x16x32_bf16(g1, pb1, acc11, 0, 0, 0);
            acc12 = __builtin_amdgcn_mfma_f32_16x16x32_bf16(g2, pb1, acc12, 0, 0, 0);
        }
    }

    #pragma unroll
    for (int r = 0; r < 4; ++r) {
        accbuf[w][0][4 * kgrp + r][ql] = acc00[r];
        accbuf[w][0][16 + 4 * kgrp + r][ql] = acc01[r];
        accbuf[w][1][4 * kgrp + r][ql] = acc10[r];
        accbuf[w][1][16 + 4 * kgrp + r][ql] = acc11[r];
    }
    if (kgrp == 0) {
        accbuf[w][0][32][ql] = acc02[0];
        accbuf[w][0][33][ql] = acc02[1];
        accbuf[w][1][32][ql] = acc12[0];
        accbuf[w][1][33][ql] = acc12[1];
    }
    __syncthreads();

    for (int i = tid; i < 2 * 34 * 16; i += 256) {
        int t = i / 544, rem = i % 544;
        int rp = rem >> 4, qq = rem & 15;
        float v = accbuf[0][t][rp][qq] + accbuf[1][t][rp][qq]
                + accbuf[2][t][rp][qq] + accbuf[3][t][rp][qq];
        int Q = q0 + t * 16 + qq;
        if (rp < 32) {
            float s = accbuf[0][t][32][qq] + accbuf[1][t][32][qq]
                    + accbuf[2][t][32][qq] + accbuf[3][t][32][qq];
            accA[((size_t)sb * HWD + Q) * RR + rp] = v / s;
        } else if (rp == 33) {
            float s = accbuf[0][t][32][qq] + accbuf[1][t][32][qq]
                    + accbuf[2][t][32][qq] + accbuf[3][t][32][qq];
            d_out[(size_t)2 * BATCH * CCH * HWD + (size_t)sb * HWD + Q] =
                (float)(Q & 63) - v / s;
        }
    }
}

// ---------------------------------------------------------------------------
// stats1: per-block channel partial sum/sumsq of y = W_up a + b_up
// ---------------------------------------------------------------------------
__global__ __launch_bounds__(256) void stats1_kernel(
    const float* __restrict__ accA, const float* __restrict__ w_up,
    const float* __restrict__ b_up, float* __restrict__ part)
{
    __shared__ float wup_s[64][RR];
    __shared__ float bu_s[64];
    __shared__ float redS[4][64];
    __shared__ float redQ[4][64];
    int tid = threadIdx.x;
    for (int i = tid; i < 64 * RR; i += 256) wup_s[i >> 5][i & 31] = w_up[i];
    if (tid < 64) bu_s[tid] = b_up[tid];
    __syncthreads();

    int sbq = blockIdx.x * 128 + (tid >> 1);
    int ohalf = tid & 1;
    int w = tid >> 6, lane = tid & 63;

    const f32x4* ap = (const f32x4*)(accA + (size_t)sbq * RR);
    float a[RR];
    #pragma unroll
    for (int v = 0; v < 8; ++v) {
        f32x4 t4 = ap[v];
        a[4*v] = t4[0]; a[4*v+1] = t4[1]; a[4*v+2] = t4[2]; a[4*v+3] = t4[3];
    }

    #pragma unroll
    for (int oi = 0; oi < 32; ++oi) {
        int o = ohalf * 32 + oi;
        float y = bu_s[o];
        #pragma unroll
        for (int r = 0; r < RR; ++r) y += wup_s[o][r] * a[r];
        float s1 = y, s2 = y * y;
        #pragma unroll
        for (int off = 2; off <= 32; off <<= 1) {
            s1 += __shfl_xor(s1, off);
            s2 += __shfl_xor(s2, off);
        }
        if (lane < 2) { redS[w][lane * 32 + oi] = s1; redQ[w][lane * 32 + oi] = s2; }
    }
    __syncthreads();
    if (tid < 64) {
        float s1 = redS[0][tid] + redS[1][tid] + redS[2][tid] + redS[3][tid];
        float s2 = redQ[0][tid] + redQ[1][tid] + redQ[2][tid] + redQ[3][tid];
        part[((size_t)blockIdx.x * 64 + tid) * 2] = s1;
        part[((size_t)blockIdx.x * 64 + tid) * 2 + 1] = s2;
    }
}

// ---------------------------------------------------------------------------
// stats2: finalize mean/var -> scale/shift per (side, channel)
// ---------------------------------------------------------------------------
__global__ __launch_bounds__(128) void stats2_kernel(
    const float* __restrict__ part, const float* __restrict__ gamma,
    const float* __restrict__ beta, float* __restrict__ scaleArr,
    float* __restrict__ shiftArr)
{
    int tid = threadIdx.x;           // side = tid>>6, o = tid&63
    int side = tid >> 6, o = tid & 63;
    double s1 = 0.0, s2 = 0.0;
    for (int kb = 0; kb < 64; ++kb) {
        const float* pp = part + (((size_t)(side * 64 + kb)) * 64 + o) * 2;
        s1 += (double)pp[0];
        s2 += (double)pp[1];
    }
    double n = (double)(BATCH * HWD);
    double mean = s1 / n;
    double var = s2 / n - mean * mean;
    float scale = gamma[o] / sqrtf((float)var + 1e-5f);
    float shift = beta[o] - (float)mean * scale;
    scaleArr[tid] = scale;
    shiftArr[tid] = shift;
}

// ---------------------------------------------------------------------------
// apply: out = x + y*scale + shift  (recomputes y = W_up a + b_up)
// ---------------------------------------------------------------------------
__global__ __launch_bounds__(256) void apply_kernel(
    const float* __restrict__ left, const float* __restrict__ right,
    const float* __restrict__ accA, const float* __restrict__ w_up,
    const float* __restrict__ b_up, const float* __restrict__ scaleArr,
    const float* __restrict__ shiftArr, float* __restrict__ d_out)
{
    __shared__ float wup_s[64][RR];
    __shared__ float bu_s[64], sc_s[64], sh_s[64];
    int tid = threadIdx.x;
    int side = blockIdx.x >> 6;
    for (int i = tid; i < 64 * RR; i += 256) wup_s[i >> 5][i & 31] = w_up[i];
    if (tid < 64) {
        bu_s[tid] = b_up[tid];
        sc_s[tid] = scaleArr[side * 64 + tid];
        sh_s[tid] = shiftArr[side * 64 + tid];
    }
    __syncthreads();

    int sbq = blockIdx.x * 128 + (tid >> 1);
    int ohalf = tid & 1;
    int b = (sbq >> 12) & 1, px = sbq & 4095;

    const f32x4* ap = (const f32x4*)(accA + (size_t)sbq * RR);
    float a[RR];
    #pragma unroll
    for (int v = 0; v < 8; ++v) {
        f32x4 t4 = ap[v];
        a[4*v] = t4[0]; a[4*v+1] = t4[1]; a[4*v+2] = t4[2]; a[4*v+3] = t4[3];
    }

    const float* x = side ? right : left;
    float* outp = d_out + (size_t)side * (BATCH * CCH * HWD);

    #pragma unroll
    for (int oi = 0; oi < 32; ++oi) {
        int o = ohalf * 32 + oi;
        float y = bu_s[o];
        #pragma unroll
        for (int r = 0; r < RR; ++r) y += wup_s[o][r] * a[r];
        size_t off = ((size_t)b * CCH + o) * HWD + px;
        outp[off] = x[off] + y * sc_s[o] + sh_s[o];
    }
}

extern "C" void kernel_launch(void* const* d_in, const int* in_sizes, int n_in,
                              void* d_out, int out_size, void* d_ws, size_t ws_size,
                              hipStream_t stream)
{
    const float* left    = (const float*)d_in[0];
    const float* right   = (const float*)d_in[1];
    const float* pre_l   = (const float*)d_in[2];
    const float* pre_r   = (const float*)d_in[3];
    const float* query_l = (const float*)d_in[4];
    const float* key_l   = (const float*)d_in[5];
    const float* query_r = (const float*)d_in[6];
    const float* key_r   = (const float*)d_in[7];
    const float* w_theta = (const float*)d_in[8];
    const float* b_theta = (const float*)d_in[9];
    const float* w_phi   = (const float*)d_in[10];
    const float* b_phi   = (const float*)d_in[11];
    const float* w_g     = (const float*)d_in[12];
    const float* b_g     = (const float*)d_in[13];
    const float* w_up    = (const float*)d_in[14];
    const float* b_up    = (const float*)d_in[15];
    const float* gamma   = (const float*)d_in[16];
    const float* beta    = (const float*)d_in[17];

    char* ws = (char*)d_ws;
    ushort* thetaB  = (ushort*)ws;                       // 1,048,576
    ushort* phiB    = (ushort*)(ws + 1048576);           // 1,048,576
    ushort* gT2     = (ushort*)(ws + 2097152);           // 1,114,112
    float*  accA    = (float*)(ws + 3211264);            // 2,097,152
    float*  part    = (float*)(ws + 5308416);            // 65,536
    float*  scaleA  = (float*)(ws + 5373952);            // 512
    float*  shiftA  = (float*)(ws + 5374464);            // 512

    prep_kernel<<<192, 256, 0, stream>>>(left, right, pre_l, pre_r,
                                         query_l, key_l, query_r, key_r,
                                         w_theta, b_theta, w_phi, b_phi,
                                         w_g, b_g, thetaB, phiB, gT2);
    attn_kernel<<<512, 256, 0, stream>>>(thetaB, phiB, gT2, accA, (float*)d_out);
    stats1_kernel<<<128, 256, 0, stream>>>(accA, w_up, b_up, part);
    stats2_kernel<<<1, 128, 0, stream>>>(part, gamma, beta, scaleA, shiftA);
    apply_kernel<<<128, 256, 0, stream>>>(left, right, accA, w_up, b_up,
                                          scaleA, shiftA, (float*)d_out);
}